// Round 5
// baseline (1983.567 us; speedup 1.0000x reference)
//
#include <hip/hip_runtime.h>
#include <cstdint>
#include <cstddef>

#define B_Q 1024
#define N_MEM 100000
#define DIM 256
#define TOPK 16
#define CQ 128                 // queries per chunk
#define NCHUNK (B_Q / CQ)      // 8
#define BR 64                  // memory rows per gemm block tile
#define BD 32                  // d per LDS tile
#define SPLITS 64
#define SPLIT_ROWS 1563        // ceil(N_MEM / SPLITS)
#define EPSF 1e-8f
#define INV_T (1.0f / 0.07f)
#define NEG_INF (-1e30f)

#define MIN16(t) fminf(fminf(fminf(fminf(t[0],t[1]),fminf(t[2],t[3])),fminf(fminf(t[4],t[5]),fminf(t[6],t[7]))), \
                       fminf(fminf(fminf(t[8],t[9]),fminf(t[10],t[11])),fminf(fminf(t[12],t[13]),fminf(t[14],t[15]))))
#define MAX16(t) fmaxf(fmaxf(fmaxf(fmaxf(t[0],t[1]),fmaxf(t[2],t[3])),fmaxf(fmaxf(t[4],t[5]),fmaxf(t[6],t[7]))), \
                       fmaxf(fmaxf(fmaxf(t[8],t[9]),fmaxf(t[10],t[11])),fmaxf(fmaxf(t[12],t[13]),fmaxf(t[14],t[15]))))

// ---------------- norms: inv L2 norm of every memory row and query row ----------------
__global__ __launch_bounds__(256) void k_norms(const float* __restrict__ q,
                                               const float* __restrict__ m,
                                               float* __restrict__ invq,
                                               float* __restrict__ invm) {
    int wid  = blockIdx.x * 4 + (threadIdx.x >> 6);   // one wave per row
    int lane = threadIdx.x & 63;
    if (wid >= N_MEM + B_Q) return;
    const float* src = (wid < N_MEM) ? (m + (size_t)wid * DIM)
                                     : (q + (size_t)(wid - N_MEM) * DIM);
    float4 v = ((const float4*)src)[lane];            // 64 lanes x 4 = 256 floats
    float ss = v.x*v.x + v.y*v.y + v.z*v.z + v.w*v.w;
#pragma unroll
    for (int off = 32; off > 0; off >>= 1) ss += __shfl_xor(ss, off);
    if (lane == 0) {
        float inv = 1.0f / fmaxf(sqrtf(ss), EPSF);
        if (wid < N_MEM) invm[wid] = inv;
        else             invq[wid - N_MEM] = inv;
    }
}

// ---------------- fp32 GEMM: simsT[r][qc] = dot(query[q], mem[r]) * invq * invm ----------------
// block tile: 128 queries (whole chunk) x 64 rows; thread: 4q x 8r; K tiled by 32.
__global__ __launch_bounds__(256, 4) void k_gemm(const float* __restrict__ query,
                                                 const float* __restrict__ mem,
                                                 const float* __restrict__ invq,
                                                 const float* __restrict__ invm,
                                                 float* __restrict__ simsT,
                                                 int chunk) {
    __shared__ float qT[BD][132];   // [d][q]  pad 132 (528B rows, 16B aligned)
    __shared__ float mT[BD][68];    // [d][r]  pad 68  (272B rows, 16B aligned)
    const int tid = threadIdx.x;
    const int rowbase = blockIdx.x * BR;
    const int qg = tid & 31, rg = tid >> 5;
    const int q0 = qg * 4,  r0 = rg * 8;
    const int seg  = tid & 7;    // d-segment (x4 floats)
    const int lrow = tid >> 3;   // 0..31

    float acc[4][8];
#pragma unroll
    for (int i = 0; i < 4; ++i)
#pragma unroll
        for (int j = 0; j < 8; ++j) acc[i][j] = 0.f;

    const float* qbase = query + (size_t)(chunk * CQ) * DIM;

    for (int dt = 0; dt < DIM / BD; ++dt) {
        const int d0 = dt * BD;
        // stage queries: 128 rows x 32 d, transposed into LDS
#pragma unroll
        for (int p = 0; p < 4; ++p) {
            int qr = p * 32 + lrow;
            float4 v = *(const float4*)(qbase + (size_t)qr * DIM + d0 + seg * 4);
            qT[seg*4+0][qr] = v.x; qT[seg*4+1][qr] = v.y;
            qT[seg*4+2][qr] = v.z; qT[seg*4+3][qr] = v.w;
        }
        // stage memory rows: 64 x 32, transposed
#pragma unroll
        for (int p = 0; p < 2; ++p) {
            int mr = p * 32 + lrow;
            int grow = rowbase + mr;
            float4 v = make_float4(0.f, 0.f, 0.f, 0.f);
            if (grow < N_MEM) v = *(const float4*)(mem + (size_t)grow * DIM + d0 + seg * 4);
            mT[seg*4+0][mr] = v.x; mT[seg*4+1][mr] = v.y;
            mT[seg*4+2][mr] = v.z; mT[seg*4+3][mr] = v.w;
        }
        __syncthreads();
#pragma unroll
        for (int d = 0; d < BD; ++d) {
            float4 qv = *(const float4*)&qT[d][q0];
            float4 m0 = *(const float4*)&mT[d][r0];
            float4 m1 = *(const float4*)&mT[d][r0 + 4];
            float qa[4] = {qv.x, qv.y, qv.z, qv.w};
            float mb[8] = {m0.x, m0.y, m0.z, m0.w, m1.x, m1.y, m1.z, m1.w};
#pragma unroll
            for (int i = 0; i < 4; ++i)
#pragma unroll
                for (int j = 0; j < 8; ++j)
                    acc[i][j] = fmaf(qa[i], mb[j], acc[i][j]);
        }
        __syncthreads();
    }
    // epilogue: scale by inverse norms, store transposed sims (row-major over r, 128 q per row)
    float iq[4];
#pragma unroll
    for (int i = 0; i < 4; ++i) iq[i] = invq[chunk * CQ + q0 + i];
#pragma unroll
    for (int j = 0; j < 8; ++j) {
        int row = rowbase + r0 + j;
        if (row < N_MEM) {
            float im = invm[row];
            float4 s;
            s.x = acc[0][j] * iq[0] * im;
            s.y = acc[1][j] * iq[1] * im;
            s.z = acc[2][j] * iq[2] * im;
            s.w = acc[3][j] * iq[3] * im;
            *(float4*)(simsT + (size_t)row * CQ + q0) = s;
        }
    }
}

// ---------------- per-(query, split) exact top-16 ----------------
// grid (8 qgroups, 64 splits), block 256: 16 q x 16 row-lanes; per-thread exact top-16
// (16-deep unsorted min-replace), then 16-lane team extracts top-16 of 256 via LDS.
__global__ __launch_bounds__(256) void k_topk_part(const float* __restrict__ simsT,
                                                   float* __restrict__ part_v,
                                                   int* __restrict__ part_i) {
    __shared__ float lv[256 * 16];
    __shared__ int   li[256 * 16];
    const int tid = threadIdx.x;
    const int qg = blockIdx.x;         // 0..7
    const int s  = blockIdx.y;         // 0..63
    const int ql = tid & 15;
    const int rl = tid >> 4;
    const int qc = qg * 16 + ql;       // chunk-local query

    float tv[16]; int ti[16];
#pragma unroll
    for (int j = 0; j < 16; ++j) { tv[j] = NEG_INF; ti[j] = 0; }
    float cmin = NEG_INF;

    const int rstart = s * SPLIT_ROWS;
    const int rend   = min(rstart + SPLIT_ROWS, N_MEM);
    for (int r = rstart + rl; r < rend; r += 16) {
        float v = simsT[(size_t)r * CQ + qc];
        if (v > cmin) {
            bool done = false;
#pragma unroll
            for (int j = 0; j < 16; ++j) {
                bool hit = (!done) && (tv[j] == cmin);
                if (hit) { tv[j] = v; ti[j] = r; done = true; }
            }
            cmin = MIN16(tv);
        }
    }
#pragma unroll
    for (int j = 0; j < 16; ++j) { lv[tid * 16 + j] = tv[j]; li[tid * 16 + j] = ti[j]; }
    __syncthreads();

    // team phase: 16 contiguous lanes handle one query; extract top-16 of 256 candidates
    const int team = tid >> 4;         // query handled: qg*16+team
    const int trl  = tid & 15;
    float cv[16]; int ci[16];
#pragma unroll
    for (int j = 0; j < 16; ++j) {
        int src = team + 16 * trl;     // scanner threads with ql == team
        cv[j] = lv[src * 16 + j]; ci[j] = li[src * 16 + j];
    }
    const int lane = tid & 63;
    const unsigned long long gmask = 0xFFFFull << (lane & 48);
    const int qteam = qg * 16 + team;
    for (int round = 0; round < 16; ++round) {
        float mymax = MAX16(cv);
        float g = mymax;
        g = fmaxf(g, __shfl_xor(g, 1));
        g = fmaxf(g, __shfl_xor(g, 2));
        g = fmaxf(g, __shfl_xor(g, 4));
        g = fmaxf(g, __shfl_xor(g, 8));
        unsigned long long bal = __ballot(mymax == g);
        int winner = __ffsll((unsigned long long)(bal & gmask)) - 1;
        if (lane == winner) {
            bool done = false;
#pragma unroll
            for (int j = 0; j < 16; ++j) {
                bool hit = (!done) && (cv[j] == g);
                if (hit) {
                    part_v[qteam * (SPLITS * 16) + s * 16 + round] = g;
                    part_i[qteam * (SPLITS * 16) + s * 16 + round] = ci[j];
                    cv[j] = NEG_INF; done = true;
                }
            }
        }
    }
}

// ---------------- merge 64 splits x 16 -> final top-16 per query (one wave per query) ----------------
__global__ __launch_bounds__(256) void k_topk_merge(const float* __restrict__ part_v,
                                                    const int* __restrict__ part_i,
                                                    float* __restrict__ topv,
                                                    int* __restrict__ topi,
                                                    int chunk) {
    const int tid  = threadIdx.x;
    const int lane = tid & 63;
    const int qc   = blockIdx.x * 4 + (tid >> 6);
    float cv[16]; int ci[16];
#pragma unroll
    for (int t = 0; t < 16; ++t) {
        cv[t] = part_v[qc * 1024 + t * 64 + lane];
        ci[t] = part_i[qc * 1024 + t * 64 + lane];
    }
    const int qglob = chunk * CQ + qc;
    for (int round = 0; round < 16; ++round) {
        float mymax = MAX16(cv);
        float g = mymax;
#pragma unroll
        for (int off = 32; off > 0; off >>= 1) g = fmaxf(g, __shfl_xor(g, off));
        unsigned long long bal = __ballot(mymax == g);
        int winner = __ffsll(bal) - 1;
        if (lane == winner) {
            bool done = false;
#pragma unroll
            for (int j = 0; j < 16; ++j) {
                bool hit = (!done) && (cv[j] == g);
                if (hit) {
                    topv[qglob * 16 + round] = g;
                    topi[qglob * 16 + round] = ci[j];
                    cv[j] = NEG_INF; done = true;
                }
            }
        }
    }
}

// ---------------- softmax gather + subjective-logic fusion (K=2) ----------------
__global__ __launch_bounds__(256) void k_fuse(const float* __restrict__ topv,
                                              const int* __restrict__ topi,
                                              const float* __restrict__ mem_ev,
                                              const float* __restrict__ model_ev,
                                              float* __restrict__ out) {
    int q = blockIdx.x * blockDim.x + threadIdx.x;
    if (q >= B_Q) return;
    float tv[16]; int ti[16];
#pragma unroll
    for (int j = 0; j < 16; ++j) { tv[j] = topv[q * 16 + j]; ti[j] = topi[q * 16 + j]; }
    float mx = tv[0];
#pragma unroll
    for (int j = 1; j < 16; ++j) mx = fmaxf(mx, tv[j]);
    float es[16], ssum = 0.f;
#pragma unroll
    for (int j = 0; j < 16; ++j) { es[j] = expf((tv[j] - mx) * INV_T); ssum += es[j]; }
    float inv_s = 1.0f / ssum;
    float ar0 = 0.f, ar1 = 0.f;
#pragma unroll
    for (int j = 0; j < 16; ++j) {
        float w = es[j] * inv_s;
        const float* e = mem_ev + (size_t)ti[j] * 2;
        ar0 = fmaf(w, e[0], ar0);
        ar1 = fmaf(w, e[1], ar1);
    }
    float am0 = model_ev[q * 2 + 0] + 1.0f;
    float am1 = model_ev[q * 2 + 1] + 1.0f;
    float arr0 = ar0 + 1.0f, arr1 = ar1 + 1.0f;

    auto belief = [](float a0, float a1, float& b0, float& b1, float& u) {
        float S = fmaxf(a0 + a1, EPSF);
        b0 = fmaxf((a0 - 1.f) / S, 0.f);
        b1 = fmaxf((a1 - 1.f) / S, 0.f);
        u  = fminf(fmaxf(2.f / S, EPSF), 1.f - EPSF);
        float bs = b0 + b1;
        float target = fmaxf(1.f - u, EPSF);
        float sc = target / fmaxf(bs, EPSF);
        b0 *= sc; b1 *= sc;
    };
    float bm0, bm1, um, br0, br1, ur;
    belief(am0, am1, bm0, bm1, um);
    belief(arr0, arr1, br0, br1, ur);

    float total_pair = (bm0 + bm1) * (br0 + br1);
    float dot_same   = bm0 * br0 + bm1 * br1;
    float C = total_pair - dot_same;
    float S = fmaxf(1.f - C, EPSF);
    float b0 = (bm0 * br0 + bm0 * ur + br0 * um) / S;
    float b1 = (bm1 * br1 + bm1 * ur + br1 * um) / S;
    float u  = um * ur / S;
    b0 = fmaxf(b0, 0.f); b1 = fmaxf(b1, 0.f);
    u = fminf(fmaxf(u, EPSF), 1.f - EPSF);
    float bs = b0 + b1;
    float sc = (1.f - u) / fmaxf(bs, EPSF);
    b0 *= sc; b1 *= sc;
    float Sf = 2.f / u;
    float a0 = b0 * Sf + 1.f, a1 = b1 * Sf + 1.f;
    out[q * 2 + 0] = fmaxf(a0, 1.f + EPSF);
    out[q * 2 + 1] = fmaxf(a1, 1.f + EPSF);
}

// ---------------- launch ----------------
extern "C" void kernel_launch(void* const* d_in, const int* in_sizes, int n_in,
                              void* d_out, int out_size, void* d_ws, size_t ws_size,
                              hipStream_t stream) {
    const float* query    = (const float*)d_in[0];
    const float* mem      = (const float*)d_in[1];
    const float* mem_ev   = (const float*)d_in[2];
    const float* model_ev = (const float*)d_in[3];
    char* ws = (char*)d_ws;
    // ws layout (bytes): invq 4K | invm 400K | part_v 512K | part_i 512K | topv 64K | topi 64K | simsT 51.2M
    float* invq   = (float*)(ws + 0);
    float* invm   = (float*)(ws + 4096);
    float* part_v = (float*)(ws + 404480);
    int*   part_i = (int*)  (ws + 404480 + 524288);
    float* topv   = (float*)(ws + 1453056);
    int*   topi   = (int*)  (ws + 1518592);
    float* simsT  = (float*)(ws + 1585152);            // total ~52.8 MB

    k_norms<<<(N_MEM + B_Q + 3) / 4, 256, 0, stream>>>(query, mem, invq, invm);
    for (int c = 0; c < NCHUNK; ++c) {
        k_gemm<<<dim3((N_MEM + BR - 1) / BR), 256, 0, stream>>>(query, mem, invq, invm, simsT, c);
        k_topk_part<<<dim3(8, SPLITS), 256, 0, stream>>>(simsT, part_v, part_i);
        k_topk_merge<<<32, 256, 0, stream>>>(part_v, part_i, topv, topi, c);
    }
    k_fuse<<<4, 256, 0, stream>>>(topv, topi, mem_ev, model_ev, (float*)d_out);
}